// Round 14
// baseline (210.224 us; speedup 1.0000x reference)
//
#include <hip/hip_runtime.h>
#include <hip/hip_bf16.h>

#define NN 50000
#define DEG 16
#define EE (NN*DEG)
#define CHUNKS 3125   // NN/16

typedef unsigned int uint;
typedef unsigned short ushort;
typedef __attribute__((ext_vector_type(8))) short bf16x8;
typedef __attribute__((ext_vector_type(4))) float f32x4;

__device__ inline ushort f2b(float f){
  return __bfloat16_as_ushort(__float2bfloat16(f));
}
__device__ inline float b2f(uint lo16){ return __uint_as_float(lo16 << 16); }
__device__ inline float bhi(uint v){ return __uint_as_float(v & 0xffff0000u); }
__device__ inline void nt_store4(float* p, float a, float b, float c, float d){
  f32x4 v = {a, b, c, d};
  __builtin_nontemporal_store(v, (f32x4*)p);
}

// K0: convert W (128x64 fp32) into MFMA A-operand fragment order, once.
// Block (0,0) also resets the attn completion counter (every call; replay-safe).
__global__ __launch_bounds__(256) void prep_kernel(
    const float* __restrict__ W0, const float* __restrict__ W1,
    uint4* __restrict__ wf, uint* __restrict__ counter)
{
  const int pass = blockIdx.y;
  if (pass == 0 && blockIdx.x == 0 && threadIdx.x == 0) *counter = 0;
  const float* W = pass ? W1 : W0;
  const int t    = threadIdx.x;
  const int f    = blockIdx.x*4 + (t >> 6);   // fragment 0..15
  const int lane = t & 63;
  const int kt = f >> 2, nt = f & 3;
  const int n  = nt*16 + (lane & 15);
  const int k0 = kt*32 + (lane >> 4)*8;
  uint4 pk;
  ushort* ps = (ushort*)&pk;
  #pragma unroll
  for (int j = 0; j < 8; j++) ps[j] = f2b(W[(k0 + j)*64 + n]);
  wf[(pass*16 + f)*64 + lane] = pk;
}

// K1: bf16 MFMA GEMM, 2 chunks per wave, inputs prefetched, scores inline.
// Epilogue: LDS-transpose -> coalesced uint4 table stores + fp32 first-half
// output (nontemporal; identical bf16-rounded values as the table).
__global__ __launch_bounds__(256) void gemm_mfma_kernel(
    const float* __restrict__ in0, const float* __restrict__ in1,
    const uint4* __restrict__ wf,
    const float* __restrict__ a0,  const float* __restrict__ a1,
    ushort* __restrict__ hev,
    float* __restrict__ s1ne, float* __restrict__ s2ne,
    float* __restrict__ outp)
{
  const int pass = blockIdx.y;
  const float* in = pass ? in1 : in0;
  const float* av = pass ? a1  : a0;
  float* outhalf  = outp + (long)pass * NN * 128;

  const int tid  = threadIdx.x;
  const int wv   = tid >> 6;
  const int lane = tid & 63;
  const int g    = lane >> 4;
  const int c    = lane & 15;

  __shared__ ushort tile[4][16][72];   // rows 16B-aligned (144B stride)

  const int w   = blockIdx.x*4 + wv;   // wave id
  const int chA = w*2;
  const int chB = chA + 1;
  if (chA >= CHUNKS) return;
  const bool hasB = (chB < CHUNKS);

  // W fragments (hot in L1/L2), reused for both chunks
  bf16x8 wfrag[16];
  const uint4* wfp = wf + (long)pass*16*64 + lane;
  #pragma unroll
  for (int f = 0; f < 16; f++) {
    uint4 v = wfp[f*64];
    wfrag[f] = *(bf16x8*)&v;
  }
  // per-lane attention coefficients for features nt*16 + g*4 + v
  float a1r[4][4], a2r[4][4];
  #pragma unroll
  for (int nt = 0; nt < 4; nt++)
    #pragma unroll
    for (int v = 0; v < 4; v++) {
      a1r[nt][v] = av[nt*16 + g*4 + v];
      a2r[nt][v] = av[64 + nt*16 + g*4 + v];
    }

  // issue BOTH chunks' input loads up front
  float4 aldA[8], aldB[8];
  {
    const float* rowA = in + (long)(chA*16 + c)*128 + g*8;
    #pragma unroll
    for (int kt = 0; kt < 4; kt++) {
      aldA[kt*2]   = *(const float4*)(rowA + kt*32);
      aldA[kt*2+1] = *(const float4*)(rowA + kt*32 + 4);
    }
  }
  if (hasB) {
    const float* rowB = in + (long)(chB*16 + c)*128 + g*8;
    #pragma unroll
    for (int kt = 0; kt < 4; kt++) {
      aldB[kt*2]   = *(const float4*)(rowB + kt*32);
      aldB[kt*2+1] = *(const float4*)(rowB + kt*32 + 4);
    }
  }

#define COMPUTE_STORE(ald, ch) { \
    f32x4 acc[4]; \
    _Pragma("unroll") \
    for (int nt = 0; nt < 4; nt++) acc[nt] = (f32x4){0.f, 0.f, 0.f, 0.f}; \
    _Pragma("unroll") \
    for (int kt = 0; kt < 4; kt++) { \
      const float4 u = ald[kt*2], x = ald[kt*2+1]; \
      bf16x8 af; \
      af[0] = (short)f2b(u.x); af[1] = (short)f2b(u.y); \
      af[2] = (short)f2b(u.z); af[3] = (short)f2b(u.w); \
      af[4] = (short)f2b(x.x); af[5] = (short)f2b(x.y); \
      af[6] = (short)f2b(x.z); af[7] = (short)f2b(x.w); \
      _Pragma("unroll") \
      for (int nt = 0; nt < 4; nt++) \
        acc[nt] = __builtin_amdgcn_mfma_f32_16x16x32_bf16(wfrag[kt*4+nt], af, acc[nt], 0, 0, 0); \
    } \
    /* scores: per-lane partial over its 16 features, reduce over g */ \
    float t1 = 0.f, t2 = 0.f; \
    _Pragma("unroll") \
    for (int nt = 0; nt < 4; nt++) \
      _Pragma("unroll") \
      for (int v = 0; v < 4; v++) { \
        t1 = fmaf(acc[nt][v], a1r[nt][v], t1); \
        t2 = fmaf(acc[nt][v], a2r[nt][v], t2); \
      } \
    t1 += __shfl_xor(t1, 16); t1 += __shfl_xor(t1, 32); \
    t2 += __shfl_xor(t2, 16); t2 += __shfl_xor(t2, 32); \
    if (lane < 16) { \
      s1ne[(long)((ch)*16 + lane)*2 + pass] = t1; \
      s2ne[(long)((ch)*16 + lane)*2 + pass] = t2; \
    } \
    /* lane (g,c): out[row ch*16+c][feat nt*16+g*4+v] -> LDS transpose */ \
    ushort* tp = &tile[wv][c][g*4]; \
    _Pragma("unroll") \
    for (int nt = 0; nt < 4; nt++) { \
      uint2 pkv; \
      pkv.x = (uint)f2b(acc[nt][0]) | ((uint)f2b(acc[nt][1]) << 16); \
      pkv.y = (uint)f2b(acc[nt][2]) | ((uint)f2b(acc[nt][3]) << 16); \
      *(uint2*)(tp + nt*16) = pkv; \
    } \
    /* read out: 128 uint4 (16 rows x 8 blocks of 8 ushorts), 2/lane. */ \
    /* Each also expands to fp32 first-half output (nontemporal). */ \
    _Pragma("unroll") \
    for (int q = 0; q < 2; q++) { \
      const int idx = q*64 + lane; \
      const int row = idx >> 3, col = idx & 7; \
      uint4 val = *(const uint4*)&tile[wv][row][col*8]; \
      *(uint4*)(hev + (long)((ch)*16 + row)*128 + pass*64 + col*8) = val; \
      float* ob = outhalf + (long)((ch)*16 + row)*128 + col*8; \
      nt_store4(ob,     b2f(val.x & 0xffffu), bhi(val.x), \
                        b2f(val.y & 0xffffu), bhi(val.y)); \
      nt_store4(ob + 4, b2f(val.z & 0xffffu), bhi(val.z), \
                        b2f(val.w & 0xffffu), bhi(val.w)); \
    } \
  }

  COMPUTE_STORE(aldA, chA);
  if (hasB) COMPUTE_STORE(aldB, chB);
#undef COMPUTE_STORE
}

// K2: one wave = 4 nodes (64 edges). 2-stage pipelined gather; nontemporal
// output stores. Last block (atomic counter) folds the variance finalize.
__global__ __launch_bounds__(256) void attn_kernel(
    const uint* __restrict__ hev,   // [NN][64] uints = [NN][128] bf16 (hv | ev)
    const float2* __restrict__ s1ne, const float2* __restrict__ s2ne,
    const int* __restrict__ edges,
    float* __restrict__ outp, double* __restrict__ partials,
    uint* __restrict__ counter)
{
  const int tid  = threadIdx.x;
  const int wv   = tid >> 6;
  const int lane = tid & 63;
  const int j    = lane >> 4;      // sub-node 0..3
  const int cl   = lane & 15;      // 16-lane column-block index
  double a_qn = 0.0, a_qe = 0.0;
  float* node_out = outp;
  float* edge_out = outp + (long)NN*128;
  const int NG = NN/4;             // 12500 groups

#define LOADT(dest, T) { \
    _Pragma("unroll") \
    for (int m = 0; m < 4; m++) { \
      const int sl = (T)*16 + m*4 + j; \
      const int d  = __shfl(dst, sl); \
      dest[m] = *(const uint4*)(hev + (long)d*64 + cl*4); \
    } }

#define COMB(T, src) { \
    float ac[8]; \
    _Pragma("unroll") for (int u = 0; u < 8; u++) ac[u] = 0.f; \
    _Pragma("unroll") \
    for (int m = 0; m < 4; m++) { \
      const int sl = (T)*16 + m*4 + j; \
      const float w2n = __shfl(wn, sl); \
      const float w2e = __shfl(we, sl); \
      const float wk  = (cl < 8) ? w2n : w2e; \
      const uint4 v = src[m]; \
      ac[0] = fmaf(wk, b2f(v.x & 0xffffu), ac[0]); \
      ac[1] = fmaf(wk, bhi(v.x),           ac[1]); \
      ac[2] = fmaf(wk, b2f(v.y & 0xffffu), ac[2]); \
      ac[3] = fmaf(wk, bhi(v.y),           ac[3]); \
      ac[4] = fmaf(wk, b2f(v.z & 0xffffu), ac[4]); \
      ac[5] = fmaf(wk, bhi(v.z),           ac[5]); \
      ac[6] = fmaf(wk, b2f(v.w & 0xffffu), ac[6]); \
      ac[7] = fmaf(wk, bhi(v.w),           ac[7]); \
    } \
    _Pragma("unroll") \
    for (int u = 0; u < 8; u++) { \
      ac[u] += __shfl_xor(ac[u], 16); \
      ac[u] += __shfl_xor(ac[u], 32); \
    } \
    if (lane < 16) { \
      float* base = ((cl < 8) ? node_out : edge_out) \
                    + (long)(i0 + (T))*128 + 64 + 8*(cl & 7); \
      nt_store4(base,     ac[0], ac[1], ac[2], ac[3]); \
      nt_store4(base + 4, ac[4], ac[5], ac[6], ac[7]); \
    } }

  for (int grp = blockIdx.x*4 + wv; grp < NG; grp += gridDim.x*4) {
    const int i0 = grp*4;
    const int dst = edges[((long)i0*16 + lane)*2 + 1];
    const float2 s1v = s1ne[i0 + j];
    const float2 gsc = s2ne[dst];
    float xn = s1v.x + gsc.x;
    float xe = s1v.y + gsc.y;
    xn = xn > 0.f ? xn : 0.2f*xn;
    xe = xe > 0.f ? xe : 0.2f*xe;
    xn = fminf(fmaxf(xn, -2.f), 2.f);
    xe = fminf(fmaxf(xe, -2.f), 2.f);
    const float an = expf(xn);
    const float ae = expf(xe);
    float sn = an, se = ae;
    #pragma unroll
    for (int off = 1; off < 16; off <<= 1) {
      sn += __shfl_xor(sn, off);
      se += __shfl_xor(se, off);
    }
    const float wn = an / sn;
    const float we = ae / se;

    // issue first 8 gather loads before any dependent compute
    uint4 g0[4], g1[4];
    LOADT(g0, 0);
    LOADT(g1, 1);

    // overlap: variance reduction under gather latency
    float rq = wn*wn, re = we*we;
    #pragma unroll
    for (int off = 1; off < 64; off <<= 1) {
      rq += __shfl_xor(rq, off);
      re += __shfl_xor(re, off);
    }
    if (lane == 0) { a_qn += (double)rq; a_qe += (double)re; }

    // rotate: combine t while t+2 loads
    COMB(0, g0);
    LOADT(g0, 2);
    COMB(1, g1);
    LOADT(g1, 3);
    COMB(2, g0);
    COMB(3, g1);
  }
#undef LOADT
#undef COMB

  __shared__ double red[4][2];
  if (lane == 0) { red[wv][0] = a_qn; red[wv][1] = a_qe; }
  __syncthreads();
  if (tid == 0) {
    double t0 = 0, t1 = 0;
    #pragma unroll
    for (int w = 0; w < 4; w++) { t0 += red[w][0]; t1 += red[w][1]; }
    double* p = partials + (long)blockIdx.x*2;
    p[0] = t0; p[1] = t1;
  }

  // last-block finalize (deterministic: fixed-order sum over partials)
  __shared__ uint lastFlag;
  if (tid == 0) {
    __threadfence();
    uint prev = atomicAdd(counter, 1u);
    lastFlag = (prev == (uint)gridDim.x - 1u) ? 1u : 0u;
  }
  __syncthreads();
  if (lastFlag) {
    double l0 = 0, l1 = 0;
    for (int b = tid; b < (int)gridDim.x; b += 256) {
      l0 += partials[b*2+0];
      l1 += partials[b*2+1];
    }
    __shared__ double red2[256][2];
    red2[tid][0] = l0; red2[tid][1] = l1;
    __syncthreads();
    for (int s = 128; s > 0; s >>= 1) {
      if (tid < s) {
        red2[tid][0] += red2[tid+s][0];
        red2[tid][1] += red2[tid+s][1];
      }
      __syncthreads();
    }
    if (tid == 0) {
      const double E = (double)EE;
      const double S = (double)NN;   // sum of normalized weights == 1 per node
      double varn = (red2[0][0] - S*S/E) / (E - 1.0);
      double vare = (red2[0][1] - S*S/E) / (E - 1.0);
      outp[(long)NN*256 + 0] = (float)varn;
      outp[(long)NN*256 + 1] = (float)vare;
      *counter = 0;                  // self-reset for next replay
    }
  }
}

extern "C" void kernel_launch(void* const* d_in, const int* in_sizes, int n_in,
                              void* d_out, int out_size, void* d_ws, size_t ws_size,
                              hipStream_t stream)
{
  const float* node_fts = (const float*)d_in[0];
  const float* edge_fts = (const float*)d_in[1];
  const int*   edges    = (const int*)d_in[2];
  const float* W_node   = (const float*)d_in[3];
  const float* W_edge   = (const float*)d_in[4];
  const float* a_node   = (const float*)d_in[5];
  const float* a_edge   = (const float*)d_in[6];

  char* ws = (char*)d_ws;
  ushort* hev = (ushort*)(ws);                       // 12.8 MB interleaved table
  float* s1ne = (float*)(ws + 12800000);
  float* s2ne = (float*)(ws + 13200000);
  uint*  counter = (uint*)(ws + 13599744);
  double* partials = (double*)(ws + 13600000);
  uint4* wf = (uint4*)(ws + 14000000);               // 32 KB fragment-ordered W
  float* outp = (float*)d_out;

  hipLaunchKernelGGL(prep_kernel, dim3(4, 2), dim3(256), 0, stream,
                     W_node, W_edge, wf, counter);
  hipLaunchKernelGGL(gemm_mfma_kernel, dim3(391, 2), dim3(256), 0, stream,
                     node_fts, edge_fts, wf, a_node, a_edge,
                     hev, s1ne, s2ne, outp);
  const int AB = 3125;
  hipLaunchKernelGGL(attn_kernel, dim3(AB), dim3(256), 0, stream,
                     (const uint*)hev,
                     (const float2*)s1ne, (const float2*)s2ne,
                     edges, outp, partials, counter);
}

// Round 15
// 62.809 us; speedup vs baseline: 3.3470x; 3.3470x over previous
//
#include <hip/hip_runtime.h>
#include <hip/hip_bf16.h>

#define NN 50000
#define DEG 16
#define EE (NN*DEG)
#define CHUNKS 3125   // NN/16

typedef unsigned int uint;
typedef unsigned short ushort;
typedef __attribute__((ext_vector_type(8))) short bf16x8;
typedef __attribute__((ext_vector_type(4))) float f32x4;

__device__ inline ushort f2b(float f){
  return __bfloat16_as_ushort(__float2bfloat16(f));
}
__device__ inline float b2f(uint lo16){ return __uint_as_float(lo16 << 16); }
__device__ inline float bhi(uint v){ return __uint_as_float(v & 0xffff0000u); }
__device__ inline void nt_store4(float* p, float a, float b, float c, float d){
  f32x4 v = {a, b, c, d};
  __builtin_nontemporal_store(v, (f32x4*)p);
}

// K0: convert W (128x64 fp32) into MFMA A-operand fragment order, once.
__global__ __launch_bounds__(256) void prep_kernel(
    const float* __restrict__ W0, const float* __restrict__ W1,
    uint4* __restrict__ wf)
{
  const int pass = blockIdx.y;
  const float* W = pass ? W1 : W0;
  const int t    = threadIdx.x;
  const int f    = blockIdx.x*4 + (t >> 6);   // fragment 0..15
  const int lane = t & 63;
  const int kt = f >> 2, nt = f & 3;
  const int n  = nt*16 + (lane & 15);
  const int k0 = kt*32 + (lane >> 4)*8;
  uint4 pk;
  ushort* ps = (ushort*)&pk;
  #pragma unroll
  for (int j = 0; j < 8; j++) ps[j] = f2b(W[(k0 + j)*64 + n]);
  wf[(pass*16 + f)*64 + lane] = pk;
}

// K1: bf16 MFMA GEMM, 2 chunks per wave, inputs prefetched, scores inline.
// Epilogue: LDS-transpose -> coalesced uint4 table stores + fp32 first-half
// output (nontemporal; identical bf16-rounded values as the table).
__global__ __launch_bounds__(256) void gemm_mfma_kernel(
    const float* __restrict__ in0, const float* __restrict__ in1,
    const uint4* __restrict__ wf,
    const float* __restrict__ a0,  const float* __restrict__ a1,
    ushort* __restrict__ hev,
    float* __restrict__ s1ne, float* __restrict__ s2ne,
    float* __restrict__ outp)
{
  const int pass = blockIdx.y;
  const float* in = pass ? in1 : in0;
  const float* av = pass ? a1  : a0;
  float* outhalf  = outp + (long)pass * NN * 128;

  const int tid  = threadIdx.x;
  const int wv   = tid >> 6;
  const int lane = tid & 63;
  const int g    = lane >> 4;
  const int c    = lane & 15;

  __shared__ ushort tile[4][16][72];   // rows 16B-aligned (144B stride)

  const int w   = blockIdx.x*4 + wv;   // wave id
  const int chA = w*2;
  const int chB = chA + 1;
  if (chA >= CHUNKS) return;
  const bool hasB = (chB < CHUNKS);

  // W fragments (hot in L1/L2), reused for both chunks
  bf16x8 wfrag[16];
  const uint4* wfp = wf + (long)pass*16*64 + lane;
  #pragma unroll
  for (int f = 0; f < 16; f++) {
    uint4 v = wfp[f*64];
    wfrag[f] = *(bf16x8*)&v;
  }
  // per-lane attention coefficients for features nt*16 + g*4 + v
  float a1r[4][4], a2r[4][4];
  #pragma unroll
  for (int nt = 0; nt < 4; nt++)
    #pragma unroll
    for (int v = 0; v < 4; v++) {
      a1r[nt][v] = av[nt*16 + g*4 + v];
      a2r[nt][v] = av[64 + nt*16 + g*4 + v];
    }

  // issue BOTH chunks' input loads up front
  float4 aldA[8], aldB[8];
  {
    const float* rowA = in + (long)(chA*16 + c)*128 + g*8;
    #pragma unroll
    for (int kt = 0; kt < 4; kt++) {
      aldA[kt*2]   = *(const float4*)(rowA + kt*32);
      aldA[kt*2+1] = *(const float4*)(rowA + kt*32 + 4);
    }
  }
  if (hasB) {
    const float* rowB = in + (long)(chB*16 + c)*128 + g*8;
    #pragma unroll
    for (int kt = 0; kt < 4; kt++) {
      aldB[kt*2]   = *(const float4*)(rowB + kt*32);
      aldB[kt*2+1] = *(const float4*)(rowB + kt*32 + 4);
    }
  }

#define COMPUTE_STORE(ald, ch) { \
    f32x4 acc[4]; \
    _Pragma("unroll") \
    for (int nt = 0; nt < 4; nt++) acc[nt] = (f32x4){0.f, 0.f, 0.f, 0.f}; \
    _Pragma("unroll") \
    for (int kt = 0; kt < 4; kt++) { \
      const float4 u = ald[kt*2], x = ald[kt*2+1]; \
      bf16x8 af; \
      af[0] = (short)f2b(u.x); af[1] = (short)f2b(u.y); \
      af[2] = (short)f2b(u.z); af[3] = (short)f2b(u.w); \
      af[4] = (short)f2b(x.x); af[5] = (short)f2b(x.y); \
      af[6] = (short)f2b(x.z); af[7] = (short)f2b(x.w); \
      _Pragma("unroll") \
      for (int nt = 0; nt < 4; nt++) \
        acc[nt] = __builtin_amdgcn_mfma_f32_16x16x32_bf16(wfrag[kt*4+nt], af, acc[nt], 0, 0, 0); \
    } \
    /* scores: per-lane partial over its 16 features, reduce over g */ \
    float t1 = 0.f, t2 = 0.f; \
    _Pragma("unroll") \
    for (int nt = 0; nt < 4; nt++) \
      _Pragma("unroll") \
      for (int v = 0; v < 4; v++) { \
        t1 = fmaf(acc[nt][v], a1r[nt][v], t1); \
        t2 = fmaf(acc[nt][v], a2r[nt][v], t2); \
      } \
    t1 += __shfl_xor(t1, 16); t1 += __shfl_xor(t1, 32); \
    t2 += __shfl_xor(t2, 16); t2 += __shfl_xor(t2, 32); \
    if (lane < 16) { \
      s1ne[(long)((ch)*16 + lane)*2 + pass] = t1; \
      s2ne[(long)((ch)*16 + lane)*2 + pass] = t2; \
    } \
    /* lane (g,c): out[row ch*16+c][feat nt*16+g*4+v] -> LDS transpose */ \
    ushort* tp = &tile[wv][c][g*4]; \
    _Pragma("unroll") \
    for (int nt = 0; nt < 4; nt++) { \
      uint2 pkv; \
      pkv.x = (uint)f2b(acc[nt][0]) | ((uint)f2b(acc[nt][1]) << 16); \
      pkv.y = (uint)f2b(acc[nt][2]) | ((uint)f2b(acc[nt][3]) << 16); \
      *(uint2*)(tp + nt*16) = pkv; \
    } \
    /* read out: 128 uint4 (16 rows x 8 blocks of 8 ushorts), 2/lane. */ \
    /* Each also expands to fp32 first-half output (nontemporal). */ \
    _Pragma("unroll") \
    for (int q = 0; q < 2; q++) { \
      const int idx = q*64 + lane; \
      const int row = idx >> 3, col = idx & 7; \
      uint4 val = *(const uint4*)&tile[wv][row][col*8]; \
      *(uint4*)(hev + (long)((ch)*16 + row)*128 + pass*64 + col*8) = val; \
      float* ob = outhalf + (long)((ch)*16 + row)*128 + col*8; \
      nt_store4(ob,     b2f(val.x & 0xffffu), bhi(val.x), \
                        b2f(val.y & 0xffffu), bhi(val.y)); \
      nt_store4(ob + 4, b2f(val.z & 0xffffu), bhi(val.z), \
                        b2f(val.w & 0xffffu), bhi(val.w)); \
    } \
  }

  COMPUTE_STORE(aldA, chA);
  if (hasB) COMPUTE_STORE(aldB, chB);
#undef COMPUTE_STORE
}

// K2: one wave = 4 nodes (64 edges). 2-stage pipelined gather; second-half
// outputs only, nontemporal stores (keep L2 for the gather table).
__global__ __launch_bounds__(256) void attn_kernel(
    const uint* __restrict__ hev,   // [NN][64] uints = [NN][128] bf16 (hv | ev)
    const float2* __restrict__ s1ne, const float2* __restrict__ s2ne,
    const int* __restrict__ edges,
    float* __restrict__ outp, double* __restrict__ partials)
{
  const int tid  = threadIdx.x;
  const int wv   = tid >> 6;
  const int lane = tid & 63;
  const int j    = lane >> 4;      // sub-node 0..3
  const int cl   = lane & 15;      // 16-lane column-block index
  double a_qn = 0.0, a_qe = 0.0;
  float* node_out = outp;
  float* edge_out = outp + (long)NN*128;
  const int NG = NN/4;             // 12500 groups

#define LOADT(dest, T) { \
    _Pragma("unroll") \
    for (int m = 0; m < 4; m++) { \
      const int sl = (T)*16 + m*4 + j; \
      const int d  = __shfl(dst, sl); \
      dest[m] = *(const uint4*)(hev + (long)d*64 + cl*4); \
    } }

#define COMB(T, src) { \
    float ac[8]; \
    _Pragma("unroll") for (int u = 0; u < 8; u++) ac[u] = 0.f; \
    _Pragma("unroll") \
    for (int m = 0; m < 4; m++) { \
      const int sl = (T)*16 + m*4 + j; \
      const float w2n = __shfl(wn, sl); \
      const float w2e = __shfl(we, sl); \
      const float wk  = (cl < 8) ? w2n : w2e; \
      const uint4 v = src[m]; \
      ac[0] = fmaf(wk, b2f(v.x & 0xffffu), ac[0]); \
      ac[1] = fmaf(wk, bhi(v.x),           ac[1]); \
      ac[2] = fmaf(wk, b2f(v.y & 0xffffu), ac[2]); \
      ac[3] = fmaf(wk, bhi(v.y),           ac[3]); \
      ac[4] = fmaf(wk, b2f(v.z & 0xffffu), ac[4]); \
      ac[5] = fmaf(wk, bhi(v.z),           ac[5]); \
      ac[6] = fmaf(wk, b2f(v.w & 0xffffu), ac[6]); \
      ac[7] = fmaf(wk, bhi(v.w),           ac[7]); \
    } \
    _Pragma("unroll") \
    for (int u = 0; u < 8; u++) { \
      ac[u] += __shfl_xor(ac[u], 16); \
      ac[u] += __shfl_xor(ac[u], 32); \
    } \
    if (lane < 16) { \
      float* base = ((cl < 8) ? node_out : edge_out) \
                    + (long)(i0 + (T))*128 + 64 + 8*(cl & 7); \
      nt_store4(base,     ac[0], ac[1], ac[2], ac[3]); \
      nt_store4(base + 4, ac[4], ac[5], ac[6], ac[7]); \
    } }

  for (int grp = blockIdx.x*4 + wv; grp < NG; grp += gridDim.x*4) {
    const int i0 = grp*4;
    const int dst = edges[((long)i0*16 + lane)*2 + 1];
    const float2 s1v = s1ne[i0 + j];
    const float2 gsc = s2ne[dst];
    float xn = s1v.x + gsc.x;
    float xe = s1v.y + gsc.y;
    xn = xn > 0.f ? xn : 0.2f*xn;
    xe = xe > 0.f ? xe : 0.2f*xe;
    xn = fminf(fmaxf(xn, -2.f), 2.f);
    xe = fminf(fmaxf(xe, -2.f), 2.f);
    const float an = expf(xn);
    const float ae = expf(xe);
    float sn = an, se = ae;
    #pragma unroll
    for (int off = 1; off < 16; off <<= 1) {
      sn += __shfl_xor(sn, off);
      se += __shfl_xor(se, off);
    }
    const float wn = an / sn;
    const float we = ae / se;

    // issue first 8 gather loads before any dependent compute
    uint4 g0[4], g1[4];
    LOADT(g0, 0);
    LOADT(g1, 1);

    // overlap: variance reduction under gather latency
    float rq = wn*wn, re = we*we;
    #pragma unroll
    for (int off = 1; off < 64; off <<= 1) {
      rq += __shfl_xor(rq, off);
      re += __shfl_xor(re, off);
    }
    if (lane == 0) { a_qn += (double)rq; a_qe += (double)re; }

    // rotate: combine t while t+2 loads
    COMB(0, g0);
    LOADT(g0, 2);
    COMB(1, g1);
    LOADT(g1, 3);
    COMB(2, g0);
    COMB(3, g1);
  }
#undef LOADT
#undef COMB

  __shared__ double red[4][2];
  if (lane == 0) { red[wv][0] = a_qn; red[wv][1] = a_qe; }
  __syncthreads();
  if (tid == 0) {
    double t0 = 0, t1 = 0;
    #pragma unroll
    for (int w = 0; w < 4; w++) { t0 += red[w][0]; t1 += red[w][1]; }
    double* p = partials + (long)blockIdx.x*2;
    p[0] = t0; p[1] = t1;
  }
}

// K3: reduce partials -> the two variance scalars (sum of weights is exactly N)
__global__ __launch_bounds__(256) void finalize_kernel(
    const double* __restrict__ partials, int nparts, float* __restrict__ outp)
{
  const int tid = threadIdx.x;
  double l0 = 0, l1 = 0;
  for (int b = tid; b < nparts; b += 256) {
    l0 += partials[b*2+0]; l1 += partials[b*2+1];
  }
  __shared__ double red[256][2];
  red[tid][0] = l0; red[tid][1] = l1;
  __syncthreads();
  for (int s = 128; s > 0; s >>= 1) {
    if (tid < s) {
      red[tid][0] += red[tid+s][0];
      red[tid][1] += red[tid+s][1];
    }
    __syncthreads();
  }
  if (tid == 0) {
    const double E = (double)EE;
    const double S = (double)NN;
    double varn = (red[0][0] - S*S/E) / (E - 1.0);
    double vare = (red[0][1] - S*S/E) / (E - 1.0);
    outp[(long)NN*256 + 0] = (float)varn;
    outp[(long)NN*256 + 1] = (float)vare;
  }
}

extern "C" void kernel_launch(void* const* d_in, const int* in_sizes, int n_in,
                              void* d_out, int out_size, void* d_ws, size_t ws_size,
                              hipStream_t stream)
{
  const float* node_fts = (const float*)d_in[0];
  const float* edge_fts = (const float*)d_in[1];
  const int*   edges    = (const int*)d_in[2];
  const float* W_node   = (const float*)d_in[3];
  const float* W_edge   = (const float*)d_in[4];
  const float* a_node   = (const float*)d_in[5];
  const float* a_edge   = (const float*)d_in[6];

  char* ws = (char*)d_ws;
  ushort* hev = (ushort*)(ws);                       // 12.8 MB interleaved table
  float* s1ne = (float*)(ws + 12800000);
  float* s2ne = (float*)(ws + 13200000);
  double* partials = (double*)(ws + 13600000);
  uint4* wf = (uint4*)(ws + 14000000);               // 32 KB fragment-ordered W
  float* outp = (float*)d_out;

  hipLaunchKernelGGL(prep_kernel, dim3(4, 2), dim3(256), 0, stream,
                     W_node, W_edge, wf);
  hipLaunchKernelGGL(gemm_mfma_kernel, dim3(391, 2), dim3(256), 0, stream,
                     node_fts, edge_fts, wf, a_node, a_edge,
                     hev, s1ne, s2ne, outp);
  const int AB = 3125;
  hipLaunchKernelGGL(attn_kernel, dim3(AB), dim3(256), 0, stream,
                     (const uint*)hev,
                     (const float2*)s1ne, (const float2*)s2ne,
                     edges, outp, partials);
  hipLaunchKernelGGL(finalize_kernel, dim3(1), dim3(256), 0, stream,
                     partials, AB, outp);
}